// Round 1
// baseline (29.250 us; speedup 1.0000x reference)
//
#include <hip/hip_runtime.h>
#include <hip/hip_bf16.h>
#include <float.h>

// MeshLoss: out = mean_b,m( min_n |pc[b,m] - top[b,n]|^2 ) + mean( (bottom - fem_bottom)^2 )
// Shapes: network_mesh (4,3,32,16,32) f32, pc (4,3,16384) f32, fem_mesh (4,3,32,16,32) f32.
// top[b,n(,c)] = network_mesh[b,c, n>>5, 15, n&31]  (n in 0..1023)
// B=4, M=16384 pc points per batch, N=1024 top points per batch.
// fem term: elementwise over j=0..14 slices: 4*3*32*15*32 = 184320 floats.

#define DIST_BLOCKS_PER_BATCH 64   // 64*256 = 16384 threads = M
#define NUM_DIST_BLOCKS 256        // 4 batches * 64
#define NUM_FEM_BLOCKS  64
#define TOTAL_BLOCKS    (NUM_DIST_BLOCKS + NUM_FEM_BLOCKS)

#define NM_BATCH_STRIDE 49152      // 3*32*16*32
#define CH_STRIDE       16384      // 32*16*32 (== pc channel stride)
#define NTOP            1024
#define MPTS            16384
#define FEM_ELEMS       184320
#define FEM_VEC4        46080      // 184320/4

__device__ __forceinline__ float block_reduce_sum(float v) {
    // wave64 shuffle reduce, then cross-wave via LDS (256 threads = 4 waves)
    for (int o = 32; o > 0; o >>= 1) v += __shfl_down(v, o, 64);
    __shared__ float s[4];
    int lane = threadIdx.x & 63;
    int w    = threadIdx.x >> 6;
    if (lane == 0) s[w] = v;
    __syncthreads();
    if (threadIdx.x == 0) v = s[0] + s[1] + s[2] + s[3];
    return v;
}

__global__ __launch_bounds__(256) void meshloss_partials(
    const float* __restrict__ nm,
    const float* __restrict__ pc,
    const float* __restrict__ fem,
    float* __restrict__ ws)
{
    const int t = threadIdx.x;

    if (blockIdx.x < NUM_DIST_BLOCKS) {
        // ---------------- distance part ----------------
        __shared__ float4 top[NTOP];   // 16 KB
        const int b   = blockIdx.x >> 6;          // batch
        const int blk = blockIdx.x & 63;          // block within batch
        const float* nmb = nm + b * NM_BATCH_STRIDE;

        // stage top points (j == 15 slice) into LDS as float4 (x,y,z,0)
        for (int p = t; p < NTOP; p += 256) {
            const int i = p >> 5, k = p & 31;
            const int base = i * 512 + 480 + k;   // (i*16+15)*32 + k
            float x = nmb[0 * CH_STRIDE + base];
            float y = nmb[1 * CH_STRIDE + base];
            float z = nmb[2 * CH_STRIDE + base];
            top[p] = make_float4(x, y, z, 0.0f);
        }
        __syncthreads();

        // each thread owns one pc point
        const int m = blk * 256 + t;
        const float* pcb = pc + b * NM_BATCH_STRIDE;
        const float px = pcb[m];
        const float py = pcb[CH_STRIDE + m];
        const float pz = pcb[2 * CH_STRIDE + m];

        // 4 independent min chains for ILP
        float m0 = FLT_MAX, m1 = FLT_MAX, m2 = FLT_MAX, m3 = FLT_MAX;
        #pragma unroll 4
        for (int n = 0; n < NTOP; n += 4) {
            float4 a = top[n + 0];
            float4 c1 = top[n + 1];
            float4 c2 = top[n + 2];
            float4 c3 = top[n + 3];
            float dx, dy, dz, d;
            dx = px - a.x;  dy = py - a.y;  dz = pz - a.z;
            d = dx * dx + dy * dy + dz * dz;  m0 = fminf(m0, d);
            dx = px - c1.x; dy = py - c1.y; dz = pz - c1.z;
            d = dx * dx + dy * dy + dz * dz;  m1 = fminf(m1, d);
            dx = px - c2.x; dy = py - c2.y; dz = pz - c2.z;
            d = dx * dx + dy * dy + dz * dz;  m2 = fminf(m2, d);
            dx = px - c3.x; dy = py - c3.y; dz = pz - c3.z;
            d = dx * dx + dy * dy + dz * dz;  m3 = fminf(m3, d);
        }
        float dmin = fminf(fminf(m0, m1), fminf(m2, m3));

        float s = block_reduce_sum(dmin);
        if (t == 0) ws[blockIdx.x] = s;
    } else {
        // ---------------- fem MSE part ----------------
        // bottom slice: for each of bci=0..383 chunks (b*3*32), 480 contiguous
        // floats starting at bci*512. 480 = 120 float4, base 16B-aligned.
        const int fb = blockIdx.x - NUM_DIST_BLOCKS;   // 0..63
        const float4* nm4  = reinterpret_cast<const float4*>(nm);
        const float4* fem4 = reinterpret_cast<const float4*>(fem);
        float acc = 0.0f;
        for (int q = fb * 256 + t; q < FEM_VEC4; q += NUM_FEM_BLOCKS * 256) {
            const int bci = q / 120;
            const int rem = q - bci * 120;
            const int s   = bci * 128 + rem;   // float4 index
            float4 a = nm4[s];
            float4 f = fem4[s];
            float dx = a.x - f.x, dy = a.y - f.y, dz = a.z - f.z, dw = a.w - f.w;
            acc += dx * dx + dy * dy + dz * dz + dw * dw;
        }
        float s = block_reduce_sum(acc);
        if (t == 0) ws[blockIdx.x] = s;
    }
}

__global__ __launch_bounds__(256) void meshloss_reduce(
    const float* __restrict__ ws, float* __restrict__ out)
{
    const int t = threadIdx.x;
    // dist partials: ws[0..255], scale by 1/(B*M)=1/65536
    // fem partials:  ws[256..319], scale by 1/184320
    float v = ws[t] * (1.0f / 65536.0f);
    if (t < NUM_FEM_BLOCKS) v += ws[NUM_DIST_BLOCKS + t] * (1.0f / 184320.0f);
    v = block_reduce_sum(v);
    if (t == 0) out[0] = v;
}

extern "C" void kernel_launch(void* const* d_in, const int* in_sizes, int n_in,
                              void* d_out, int out_size, void* d_ws, size_t ws_size,
                              hipStream_t stream) {
    const float* nm  = (const float*)d_in[0];   // network_mesh
    const float* pc  = (const float*)d_in[1];   // pc
    const float* fem = (const float*)d_in[2];   // fem_mesh
    float* out = (float*)d_out;
    float* ws  = (float*)d_ws;

    meshloss_partials<<<TOTAL_BLOCKS, 256, 0, stream>>>(nm, pc, fem, ws);
    meshloss_reduce<<<1, 256, 0, stream>>>(ws, out);
}

// Round 2
// 17.178 us; speedup vs baseline: 1.7027x; 1.7027x over previous
//
#include <hip/hip_runtime.h>
#include <hip/hip_bf16.h>
#include <float.h>

// MeshLoss: out = mean_b,m( min_n |pc[b,m] - top[b,n]|^2 ) + mean( (bottom - fem_bottom)^2 )
// network_mesh (4,3,32,16,32) f32, pc (4,3,16384) f32, fem_mesh (4,3,32,16,32) f32.
// top[b,n] = network_mesh[b, :, n>>5, 15, n&31], n in [0,1024)
//
// Dist decomposition: |p-t|^2 = |p|^2 + (|t|^2 - 2 p.t).  Stage (tx,ty,tz,|t|^2)
// in LDS; per pair d' = fma(-2px,tx, fma(-2py,ty, fma(-2pz,tz, t2))) = 3 FMA.
// min_n(|p|^2 + d') = |p|^2 + min_n d'  -> add |p|^2 into the tile-partial
// (commutes with the cross-tile min).
//
// Grid: 512 dist blocks = 4 batches x 8 pc-chunks(2048 pts) x 16 top-tiles(64 tops)
//       + 64 fem blocks.  P=8 pc points/thread: each ds_read_b128 feeds 8 pairs.

#define B_BATCH        4
#define MPTS           16384
#define NTOP           1024
#define NM_BATCH_STRIDE 49152     // 3*32*16*32 (== pc batch stride 3*16384)
#define CH_STRIDE      16384

#define PC_PER_THREAD  8
#define PC_CHUNK       2048       // 256 threads * 8
#define N_CHUNKS       8          // 16384 / 2048
#define N_TILES        16
#define TILE_TOPS      64         // 1024 / 16

#define NUM_DIST_BLOCKS (B_BATCH * N_CHUNKS * N_TILES)   // 512
#define NUM_FEM_BLOCKS  64
#define TOTAL_BLOCKS    (NUM_DIST_BLOCKS + NUM_FEM_BLOCKS)

#define TOTAL_M        65536      // B*M
#define FEM_VEC4       46080      // 184320/4

// d_ws layout (floats):
//   [0, 16*65536)                 tile partial mins (+|p|^2)
//   [WS_BSUM, WS_BSUM+256)        reduce-pass block sums
//   [WS_FEM,  WS_FEM+64)          fem block partial sums
#define WS_BSUM  (N_TILES * TOTAL_M)
#define WS_FEM   (WS_BSUM + 256)

__device__ __forceinline__ float block_reduce_sum(float v) {
    for (int o = 32; o > 0; o >>= 1) v += __shfl_down(v, o, 64);
    __shared__ float s[4];
    int lane = threadIdx.x & 63;
    int w    = threadIdx.x >> 6;
    if (lane == 0) s[w] = v;
    __syncthreads();
    if (threadIdx.x == 0) v = s[0] + s[1] + s[2] + s[3];
    return v;
}

__global__ __launch_bounds__(256) void meshloss_partials(
    const float* __restrict__ nm,
    const float* __restrict__ pc,
    const float* __restrict__ fem,
    float* __restrict__ ws)
{
    const int t = threadIdx.x;

    if (blockIdx.x < NUM_DIST_BLOCKS) {
        // ---- distance tile partials ----
        __shared__ float4 top[TILE_TOPS];   // 1 KB
        const int bid   = blockIdx.x;
        const int b     = bid >> 7;                 // / 128
        const int rem   = bid & 127;
        const int chunk = rem >> 4;                 // pc chunk (8)
        const int tile  = rem & 15;                 // top tile (16)

        const float* nmb = nm + b * NM_BATCH_STRIDE;
        if (t < TILE_TOPS) {
            const int p = tile * TILE_TOPS + t;
            const int i = p >> 5, k = p & 31;
            const int base = i * 512 + 480 + k;     // (i*16+15)*32 + k
            float x = nmb[0 * CH_STRIDE + base];
            float y = nmb[1 * CH_STRIDE + base];
            float z = nmb[2 * CH_STRIDE + base];
            top[t] = make_float4(x, y, z, x * x + y * y + z * z);
        }
        __syncthreads();

        const float* pcb = pc + b * NM_BATCH_STRIDE;
        const int mbase = chunk * PC_CHUNK + t;

        float px2[PC_PER_THREAD], py2[PC_PER_THREAD], pz2[PC_PER_THREAD];
        float pp[PC_PER_THREAD], mn[PC_PER_THREAD];
        #pragma unroll
        for (int j = 0; j < PC_PER_THREAD; ++j) {
            const int m = mbase + j * 256;
            float x = pcb[m];
            float y = pcb[CH_STRIDE + m];
            float z = pcb[2 * CH_STRIDE + m];
            pp[j]  = x * x + y * y + z * z;
            px2[j] = -2.0f * x;
            py2[j] = -2.0f * y;
            pz2[j] = -2.0f * z;
            mn[j]  = FLT_MAX;
        }

        #pragma unroll 2
        for (int n = 0; n < TILE_TOPS; n += 2) {
            float4 T0 = top[n];
            float4 T1 = top[n + 1];
            #pragma unroll
            for (int j = 0; j < PC_PER_THREAD; ++j) {
                float d0 = __builtin_fmaf(px2[j], T0.x,
                           __builtin_fmaf(py2[j], T0.y,
                           __builtin_fmaf(pz2[j], T0.z, T0.w)));
                float d1 = __builtin_fmaf(px2[j], T1.x,
                           __builtin_fmaf(py2[j], T1.y,
                           __builtin_fmaf(pz2[j], T1.z, T1.w)));
                mn[j] = fminf(mn[j], fminf(d0, d1));   // -> v_min3_f32
            }
        }

        // write tile partial (add |p|^2 here; commutes with cross-tile min)
        float* wrow = ws + tile * TOTAL_M + b * MPTS;
        #pragma unroll
        for (int j = 0; j < PC_PER_THREAD; ++j)
            wrow[mbase + j * 256] = mn[j] + pp[j];
    } else {
        // ---- fem MSE partials ----
        const int fb = blockIdx.x - NUM_DIST_BLOCKS;   // 0..63
        const float4* nm4  = reinterpret_cast<const float4*>(nm);
        const float4* fem4 = reinterpret_cast<const float4*>(fem);
        float acc = 0.0f;
        for (int q = fb * 256 + t; q < FEM_VEC4; q += NUM_FEM_BLOCKS * 256) {
            const int bci = q / 120;
            const int r   = q - bci * 120;
            const int s   = bci * 128 + r;
            float4 a = nm4[s];
            float4 f = fem4[s];
            float dx = a.x - f.x, dy = a.y - f.y, dz = a.z - f.z, dw = a.w - f.w;
            acc += dx * dx + dy * dy + dz * dz + dw * dw;
        }
        float s = block_reduce_sum(acc);
        if (t == 0) ws[WS_FEM + fb] = s;
    }
}

// min across the 16 tile partials, block-sum -> ws[WS_BSUM + blk]
__global__ __launch_bounds__(256) void meshloss_minreduce(
    const float* __restrict__ ws_in, float* __restrict__ ws)
{
    const int i = blockIdx.x * 256 + threadIdx.x;   // 0..65535
    float v = ws_in[i];
    #pragma unroll
    for (int tl = 1; tl < N_TILES; ++tl)
        v = fminf(v, ws_in[tl * TOTAL_M + i]);
    float s = block_reduce_sum(v);
    if (threadIdx.x == 0) ws[WS_BSUM + blockIdx.x] = s;
}

__global__ __launch_bounds__(256) void meshloss_final(
    const float* __restrict__ ws, float* __restrict__ out)
{
    const int t = threadIdx.x;
    float v = ws[WS_BSUM + t] * (1.0f / 65536.0f);
    if (t < NUM_FEM_BLOCKS) v += ws[WS_FEM + t] * (1.0f / 184320.0f);
    v = block_reduce_sum(v);
    if (t == 0) out[0] = v;
}

extern "C" void kernel_launch(void* const* d_in, const int* in_sizes, int n_in,
                              void* d_out, int out_size, void* d_ws, size_t ws_size,
                              hipStream_t stream) {
    const float* nm  = (const float*)d_in[0];
    const float* pc  = (const float*)d_in[1];
    const float* fem = (const float*)d_in[2];
    float* out = (float*)d_out;
    float* ws  = (float*)d_ws;

    meshloss_partials<<<TOTAL_BLOCKS, 256, 0, stream>>>(nm, pc, fem, ws);
    meshloss_minreduce<<<256, 256, 0, stream>>>(ws, ws);
    meshloss_final<<<1, 256, 0, stream>>>(ws, out);
}

// Round 3
// 16.178 us; speedup vs baseline: 1.8081x; 1.0619x over previous
//
#include <hip/hip_runtime.h>
#include <hip/hip_bf16.h>
#include <float.h>

// MeshLoss: out = mean_b,m( min_n |pc[b,m]-top[b,n]|^2 ) + mean((bottom-fem_bottom)^2)
// network_mesh (4,3,32,16,32) f32, pc (4,3,16384) f32, fem_mesh (4,3,32,16,32) f32.
// top[b,n] = network_mesh[b,:, n>>5, 15, n&31], n in [0,1024)
//
// |p-t|^2 = |p|^2 + (|t|^2 - 2 p.t): stage (tx,ty,tz,|t|^2) in LDS, per pair
// d' = fma(-2px,tx, fma(-2py,ty, fma(-2pz,tz, t2))) = 3 FMA; pairs of d's fold
// into v_min3_f32 -> 3.5 VALU/pair. |p|^2 added at the tile-partial write
// (commutes with cross-tile min).
//
// K1: 512 uniform blocks = 4 batches x 16 pc-chunks(1024) x 8 top-tiles(128).
//     P=4 pc points/thread. Tile partial mins -> ws[tile][b*16384+m] (2 MB).
//     Block 0 zeroes out[0] (K2 runs strictly after K1 -> no race).
// K2: 128 blocks: 8-way tile min + sum (each thread 2 points), fem MSE read
//     directly from inputs (float4), block-reduce combined scaled value,
//     one atomicAdd(float) per block into out[0].

#define B_BATCH         4
#define MPTS            16384
#define NM_BATCH_STRIDE 49152     // 3*32*16*32 (== pc batch stride)
#define CH_STRIDE       16384

#define PC_PER_THREAD   4
#define PC_CHUNK        1024      // 256 threads * 4
#define N_CHUNKS        16
#define N_TILES         8
#define TILE_TOPS       128       // 1024 / 8

#define NUM_DIST_BLOCKS (B_BATCH * N_CHUNKS * N_TILES)   // 512
#define NUM_RED_BLOCKS  128

#define TOTAL_M         65536     // B*M
#define FEM_VEC4        46080     // 184320/4

__device__ __forceinline__ float block_reduce_sum(float v) {
    for (int o = 32; o > 0; o >>= 1) v += __shfl_down(v, o, 64);
    __shared__ float s[4];
    int lane = threadIdx.x & 63;
    int w    = threadIdx.x >> 6;
    if (lane == 0) s[w] = v;
    __syncthreads();
    if (threadIdx.x == 0) v = s[0] + s[1] + s[2] + s[3];
    return v;
}

__global__ __launch_bounds__(256) void meshloss_dist(
    const float* __restrict__ nm,
    const float* __restrict__ pc,
    float* __restrict__ ws,
    float* __restrict__ out)
{
    const int t   = threadIdx.x;
    const int bid = blockIdx.x;

    if (bid == 0 && t == 0) out[0] = 0.0f;   // K2 runs after K1: no race

    const int b     = bid >> 7;          // /128: batch
    const int rem   = bid & 127;
    const int chunk = rem >> 3;          // 16 pc chunks
    const int tile  = rem & 7;           // 8 top tiles

    __shared__ float4 top[TILE_TOPS];    // 2 KB
    const float* nmb = nm + b * NM_BATCH_STRIDE;
    if (t < TILE_TOPS) {
        const int p = tile * TILE_TOPS + t;
        const int i = p >> 5, k = p & 31;
        const int base = i * 512 + 480 + k;     // (i*16+15)*32 + k
        float x = nmb[0 * CH_STRIDE + base];
        float y = nmb[1 * CH_STRIDE + base];
        float z = nmb[2 * CH_STRIDE + base];
        top[t] = make_float4(x, y, z, x * x + y * y + z * z);
    }
    __syncthreads();

    const float* pcb = pc + b * NM_BATCH_STRIDE;
    const int mbase = chunk * PC_CHUNK + t;

    float px2[PC_PER_THREAD], py2[PC_PER_THREAD], pz2[PC_PER_THREAD];
    float pp[PC_PER_THREAD], mn[PC_PER_THREAD];
    #pragma unroll
    for (int j = 0; j < PC_PER_THREAD; ++j) {
        const int m = mbase + j * 256;
        float x = pcb[m];
        float y = pcb[CH_STRIDE + m];
        float z = pcb[2 * CH_STRIDE + m];
        pp[j]  = x * x + y * y + z * z;
        px2[j] = -2.0f * x;
        py2[j] = -2.0f * y;
        pz2[j] = -2.0f * z;
        mn[j]  = FLT_MAX;
    }

    for (int n = 0; n < TILE_TOPS; n += 4) {
        float4 T0 = top[n + 0];
        float4 T1 = top[n + 1];
        float4 T2 = top[n + 2];
        float4 T3 = top[n + 3];
        #pragma unroll
        for (int j = 0; j < PC_PER_THREAD; ++j) {
            float d0 = __builtin_fmaf(px2[j], T0.x,
                       __builtin_fmaf(py2[j], T0.y,
                       __builtin_fmaf(pz2[j], T0.z, T0.w)));
            float d1 = __builtin_fmaf(px2[j], T1.x,
                       __builtin_fmaf(py2[j], T1.y,
                       __builtin_fmaf(pz2[j], T1.z, T1.w)));
            float d2 = __builtin_fmaf(px2[j], T2.x,
                       __builtin_fmaf(py2[j], T2.y,
                       __builtin_fmaf(pz2[j], T2.z, T2.w)));
            float d3 = __builtin_fmaf(px2[j], T3.x,
                       __builtin_fmaf(py2[j], T3.y,
                       __builtin_fmaf(pz2[j], T3.z, T3.w)));
            mn[j] = fminf(mn[j], fminf(d0, d1));   // v_min3_f32
            mn[j] = fminf(mn[j], fminf(d2, d3));   // v_min3_f32
        }
    }

    float* wrow = ws + tile * TOTAL_M + b * MPTS;
    #pragma unroll
    for (int j = 0; j < PC_PER_THREAD; ++j)
        wrow[mbase + j * 256] = mn[j] + pp[j];
}

__global__ __launch_bounds__(256) void meshloss_reduce(
    const float* __restrict__ ws,
    const float* __restrict__ nm,
    const float* __restrict__ fem,
    float* __restrict__ out)
{
    const int gid = blockIdx.x * 256 + threadIdx.x;   // 0..32767

    // ---- dist: min over 8 tiles, two points per thread (unit-stride reads) ----
    float dsum = 0.0f;
    #pragma unroll
    for (int h = 0; h < 2; ++h) {
        const int p = gid + h * 32768;
        float v = ws[p];
        #pragma unroll
        for (int tl = 1; tl < N_TILES; ++tl)
            v = fminf(v, ws[tl * TOTAL_M + p]);
        dsum += v;
    }

    // ---- fem MSE directly from inputs ----
    const float4* nm4  = reinterpret_cast<const float4*>(nm);
    const float4* fem4 = reinterpret_cast<const float4*>(fem);
    float fsum = 0.0f;
    for (int q = gid; q < FEM_VEC4; q += NUM_RED_BLOCKS * 256) {
        const int bci = q / 120;
        const int r   = q - bci * 120;
        const int s   = bci * 128 + r;
        float4 a = nm4[s];
        float4 f = fem4[s];
        float dx = a.x - f.x, dy = a.y - f.y, dz = a.z - f.z, dw = a.w - f.w;
        fsum += dx * dx + dy * dy + dz * dz + dw * dw;
    }

    float v = dsum * (1.0f / 65536.0f) + fsum * (1.0f / 184320.0f);
    float s = block_reduce_sum(v);
    if (threadIdx.x == 0) atomicAdd(out, s);
}

extern "C" void kernel_launch(void* const* d_in, const int* in_sizes, int n_in,
                              void* d_out, int out_size, void* d_ws, size_t ws_size,
                              hipStream_t stream) {
    const float* nm  = (const float*)d_in[0];
    const float* pc  = (const float*)d_in[1];
    const float* fem = (const float*)d_in[2];
    float* out = (float*)d_out;
    float* ws  = (float*)d_ws;

    meshloss_dist<<<NUM_DIST_BLOCKS, 256, 0, stream>>>(nm, pc, ws, out);
    meshloss_reduce<<<NUM_RED_BLOCKS, 256, 0, stream>>>(ws, nm, fem, out);
}